// Round 13
// baseline (247.892 us; speedup 1.0000x reference)
//
#include <hip/hip_runtime.h>
#include <cstdint>
#include <cstddef>

#define N_ 32
#define C_ 256
#define H_ 56
#define W_ 56

typedef int v4i __attribute__((ext_vector_type(4)));

template<int V> struct IC { static constexpr int value = V; };

// ---- workspace layout ----
static constexpr size_t WB_BYTES = 36ull * 16 * 64 * 16;         // 589,824
static constexpr size_t SC_OFF   = WB_BYTES;                     // 256 floats

// exact sign byte (pack_w path): 0x01 if >0, 0xff if <0, 0x00 at +-0
__device__ __forceinline__ uint32_t sgnw(uint32_t u) {
    return (u & 0x7fffffffu) ? (((uint32_t)(((int)u) >> 31) | 1u) & 0xffu) : 0u;
}
// fast sign byte (conv stage): 0x01 if >=+0, 0xff if <0 (R11: passed, 6x headroom)
__device__ __forceinline__ uint32_t sgnb(uint32_t u) {
    return ((uint32_t)(((int)u) >> 31) | 1u) & 0xffu;
}
__device__ __forceinline__ uint32_t pack4f(float4 v) {
    return sgnb(__float_as_uint(v.x)) | (sgnb(__float_as_uint(v.y)) << 8) |
           (sgnb(__float_as_uint(v.z)) << 16) | (sgnb(__float_as_uint(v.w)) << 24);
}

// ---------------- kernel 1: binarize weights into MFMA B-fragment layout ----
__global__ __launch_bounds__(256) void pack_w(const float* __restrict__ wt,
                                              char* __restrict__ wB,
                                              float* __restrict__ scaleg) {
    __shared__ double red[256];
    int o = blockIdx.x, tid = threadIdx.x;
    const float* wo = wt + (size_t)o * 2304;

    double s = 0;
    for (int j = tid; j < 2304; j += 256) s += (double)wo[j];
    red[tid] = s;
    __syncthreads();
    for (int k = 128; k > 0; k >>= 1) {
        if (tid < k) red[tid] += red[tid + k];
        __syncthreads();
    }
    double mean = red[0] / 2304.0;
    __syncthreads();

    double s2 = 0;
    for (int j = tid; j < 2304; j += 256) s2 += fabs((double)wo[j] - mean);
    red[tid] = s2;
    __syncthreads();
    for (int k = 128; k > 0; k >>= 1) {
        if (tid < k) red[tid] += red[tid + k];
        __syncthreads();
    }
    if (tid == 0) scaleg[o] = (float)(red[0] / 2304.0);

    if (tid < 144) {
        int kiter = tid >> 2, q = tid & 3;     // kiter 0..35, q = k-quad
        int tap = kiter >> 2, cb = kiter & 3;
        int kh = tap / 3, kw = tap - kh * 3;
        int words[4];
        for (int g = 0; g < 4; ++g) {
            int word = 0;
            for (int b = 0; b < 4; ++b) {
                int c = cb * 64 + q * 16 + g * 4 + b;
                double v = (double)wo[c * 9 + kh * 3 + kw];
                int sg = (v > mean) - (v < mean);
                word |= (sg & 0xff) << (8 * b);
            }
            words[g] = word;
        }
        v4i pk = {words[0], words[1], words[2], words[3]};
        *(v4i*)(wB + (((size_t)kiter * 16 + (o >> 4)) * 64 + q * 16 + (o & 15)) * 16) = pk;
    }
}

// ---------------- kernel 2: persistent FUSED pack + i8 MFMA conv ------------
// Balanced grid: 512 blocks = 256 x 4-row + 256 x 3-row (1024+768 = 1792 rows),
// dispatched 4-row-first so every CU hosts one of each = exactly 7 rows/CU at
// 2 blocks/CU (vs R12's 448 blocks leaving 32 CUs idle = 12.5% loss).
// LDS = mod-4 rolling window of 4 input rows (59,392 B): row ir at slot ir&3.
// 4-row block: iter(2 rows) + stage 2 + iter(2 rows). 3-row block: iter(2) +
// stage 1 + iter(1 row, NMF=4, stores masked at m>=56). Engine = proven
// 28-MFMA cluster + 3-deep counted B ring + per-wave k-rotation + setprio.
__global__ __launch_bounds__(256, 2) void conv_mfma(const float* __restrict__ x,
                                                    const v4i* __restrict__ wB,
                                                    const float* __restrict__ scaleg,
                                                    float* __restrict__ out) {
    __shared__ char xs[4 * 58 * 256];   // 59,392 B
    int tid = threadIdx.x;
    int wave = tid >> 6, lane = tid & 63;

    // block decode: b<256 -> 4-row species, else 3-row. XCD locality: HW maps
    // block b to XCD b%8; tile = (u&7)*32 + (u>>3) gives XCD x images 4x..4x+3
    // (both species) -> halo rows L2-local.
    int b = blockIdx.x;
    bool four = (b < 256);
    int u = four ? b : b - 256;
    int tile = (u & 7) * 32 + (u >> 3);
    int n = tile >> 3;
    int j = tile & 7;
    int h0a = four ? j * 4 : 32 + j * 3;

    // stage one interior unit: input row ir = ir0 + u/224 -> slot ir & 3
    auto unit = [&](int ir0, int uu) {
        int R   = uu / 224;
        int rem = uu - R * 224;
        int ch  = rem / 14;
        int wq  = rem - ch * 14;
        int ir  = ir0 + R;
        int slot = ir & 3;               // (-1)&3 == 3: virtual halo rows ok
        if (ir < 0 || ir > 55) {
            v4i z = {0, 0, 0, 0};
#pragma unroll
            for (int h = 0; h < 4; ++h) {
                int wp = 1 + wq * 4 + h;
                int s16 = (ch + wp) & 15;
                *(v4i*)(xs + ((size_t)(slot * 58 + wp) << 8) + (s16 << 4)) = z;
            }
            return;
        }
        const float* xb = x + ((size_t)n * C_ + ch * 16) * 3136 + ir * 56 + wq * 4;
        uint32_t sw[16];
#pragma unroll
        for (int c = 0; c < 16; ++c)
            sw[c] = pack4f(*(const float4*)(xb + (size_t)c * 3136));
        uint32_t t[4][4];
#pragma unroll
        for (int p = 0; p < 4; ++p) {
            uint32_t lo01 = __builtin_amdgcn_perm(sw[4*p+1], sw[4*p+0], 0x05010400u);
            uint32_t hi01 = __builtin_amdgcn_perm(sw[4*p+1], sw[4*p+0], 0x07030602u);
            uint32_t lo23 = __builtin_amdgcn_perm(sw[4*p+3], sw[4*p+2], 0x05010400u);
            uint32_t hi23 = __builtin_amdgcn_perm(sw[4*p+3], sw[4*p+2], 0x07030602u);
            t[p][0] = __builtin_amdgcn_perm(lo23, lo01, 0x05040100u);
            t[p][1] = __builtin_amdgcn_perm(lo23, lo01, 0x07060302u);
            t[p][2] = __builtin_amdgcn_perm(hi23, hi01, 0x05040100u);
            t[p][3] = __builtin_amdgcn_perm(hi23, hi01, 0x07060302u);
        }
#pragma unroll
        for (int h = 0; h < 4; ++h) {
            int wp = 1 + wq * 4 + h;
            int s16 = (ch + wp) & 15;
            v4i c4 = {(int)t[0][h], (int)t[1][h], (int)t[2][h], (int)t[3][h]};
            *(v4i*)(xs + ((size_t)(slot * 58 + wp) << 8) + (s16 << 4)) = c4;
        }
    };
    // halo cols wp = 0,57 for staged rows: uu in [0, rows*32)
    auto halo = [&](int ir0, int uu) {
        int r  = uu >> 5;
        int c2 = uu & 31;
        int slot = (ir0 + r) & 3;
        int wp = (c2 >> 4) * 57;
        int ch = c2 & 15;
        int s16 = (ch + wp) & 15;
        v4i z = {0, 0, 0, 0};
        *(v4i*)(xs + ((size_t)(slot * 58 + wp) << 8) + (s16 << 4)) = z;
    };

    // ---- prologue stage: input rows h0a-1 .. h0a+2 (4 rows, 896 units) ----
    if (tid < 128) halo(h0a - 1, tid);
    unit(h0a - 1, tid);
    unit(h0a - 1, tid + 256);
    unit(h0a - 1, tid + 512);
    if (tid < 128) unit(h0a - 1, tid + 768);

    // ---- engine per-lane constants ----
    int lm = lane & 15, q = lane >> 4;
    int og = wave;
    int kstart = __builtin_amdgcn_readfirstlane(wave * 9);   // 0,9,18,27

    int wof[7], ro[7], slotb[7];
#pragma unroll
    for (int mf = 0; mf < 7; ++mf) {
        int m = mf * 16 + lm;            // m = row*56 + w
        int r = m / 56;
        ro[mf]    = r;
        wof[mf]   = m - r * 56;
        slotb[mf] = q + wof[mf];
    }

    const v4i* wBw = wB + (size_t)(og * 4) * 64 + lane;   // + k*1024 + of*64

    auto wrap = [&](int t) {
        int k = kstart + t;
        if (k >= 36) k -= 36;
        if (k >= 36) k -= 36;
        return k;
    };
    auto loadB = [&](int k, v4i (&bb)[4]) {
#pragma unroll
        for (int of = 0; of < 4; ++of) bb[of] = wBw[(size_t)k * 1024 + of * 64];
    };

    // one engine iteration at output rows h0it.. (NMF=7: 2 rows; NMF=4: 1 row,
    // padded m 56..63 masked at store; its A-reads hit in-bounds stale LDS)
    auto run_iter = [&](int h0it, auto NMFC) {
        constexpr int NMF = decltype(NMFC)::value;
        v4i acc[NMF][4];
#pragma unroll
        for (int mf = 0; mf < NMF; ++mf)
#pragma unroll
            for (int of = 0; of < 4; ++of) { v4i z = {0, 0, 0, 0}; acc[mf][of] = z; }

        v4i bR0[4], bR1[4], bR2[4];
        loadB(wrap(0), bR0);
        loadB(wrap(1), bR1);
        loadB(wrap(2), bR2);

        auto step = [&](v4i (&bReg)[4], int t) {
            int k = wrap(t);
            int tap = k >> 2, cb = k & 3;
            int dh = (tap * 11) >> 5;        // tap/3 for tap<=8
            int dw = tap - dh * 3;
            int s0 = (h0it - 1 + dh) & 3;    // slot of input row for ro=0
            int s1 = (s0 + 1) & 3;           // slot for ro=1
            int p0 = s0 * 58 + dw;
            int dpr = (s1 - s0) * 58;
            int sofs = cb * 4 + dw;
            v4i a[NMF];
#pragma unroll
            for (int mf = 0; mf < NMF; ++mf) {
                int pos = p0 + ro[mf] * dpr + wof[mf];
                int s16 = (slotb[mf] + sofs) & 15;
                a[mf] = *(const v4i*)(xs + ((size_t)pos << 8) + (s16 << 4));
            }
            __builtin_amdgcn_s_setprio(1);
#pragma unroll
            for (int mf = 0; mf < NMF; ++mf)
#pragma unroll
                for (int of = 0; of < 4; ++of)
                    acc[mf][of] = __builtin_amdgcn_mfma_i32_16x16x64_i8(
                        a[mf], bReg[of], acc[mf][of], 0, 0, 0);
            __builtin_amdgcn_s_setprio(0);
            loadB(wrap(t + 3), bReg);        // refill for step t+3
        };

        for (int t3 = 0; t3 < 12; ++t3) {
            int t = t3 * 3;
            step(bR0, t);
            step(bR1, t + 1);
            step(bR2, t + 2);
        }

        // epilogue (global stores; masked only in the NMF=4 padded frag)
#pragma unroll
        for (int of = 0; of < 4; ++of) {
            int o = (og * 4 + of) * 16 + lm;
            float s = scaleg[o];
#pragma unroll
            for (int mf = 0; mf < NMF; ++mf) {
                int m  = mf * 16 + q * 4;
                if (NMF == 4 && m >= 56) continue;
                int r  = m / 56;
                int wb = m - r * 56;
                float* ob = out + ((size_t)(n * C_ + o) * H_ + h0it + r) * W_ + wb;
                float4 v = {s * (float)acc[mf][of].x, s * (float)acc[mf][of].y,
                            s * (float)acc[mf][of].z, s * (float)acc[mf][of].w};
                *(float4*)ob = v;
            }
        }
    };

    __syncthreads();                     // window rows h0a-1..h0a+2 ready
    run_iter(h0a, IC<7>{});              // outputs h0a, h0a+1

    __syncthreads();                     // all waves done reading iter0 rows
    if (four) {
        // stage rows h0a+3, h0a+4 into departing slots
        if (tid < 64) halo(h0a + 3, tid);
        unit(h0a + 3, tid);
        if (tid < 192) unit(h0a + 3, tid + 256);
        __syncthreads();
        run_iter(h0a + 2, IC<7>{});      // outputs h0a+2, h0a+3
    } else {
        // stage row h0a+3 into departing slot
        if (tid < 32) halo(h0a + 3, tid);
        if (tid < 224) unit(h0a + 3, tid);
        __syncthreads();
        run_iter(h0a + 2, IC<4>{});      // output h0a+2 (single row)
    }
}

extern "C" void kernel_launch(void* const* d_in, const int* in_sizes, int n_in,
                              void* d_out, int out_size, void* d_ws, size_t ws_size,
                              hipStream_t stream) {
    const float* x   = (const float*)d_in[0];
    const float* wgt = (const float*)d_in[1];
    float* out = (float*)d_out;
    char* ws = (char*)d_ws;

    char*  wb = ws;
    float* sg = (float*)(ws + SC_OFF);

    pack_w<<<dim3(256), dim3(256), 0, stream>>>(wgt, wb, sg);
    conv_mfma<<<dim3(512), dim3(256), 0, stream>>>(x, (const v4i*)wb, sg, out);
}

// Round 14
// 235.199 us; speedup vs baseline: 1.0540x; 1.0540x over previous
//
#include <hip/hip_runtime.h>
#include <cstdint>
#include <cstddef>

#define N_ 32
#define C_ 256
#define H_ 56
#define W_ 56

typedef int v4i __attribute__((ext_vector_type(4)));

// ---- workspace layout ----
static constexpr size_t WB_BYTES = 36ull * 16 * 64 * 16;         // 589,824
static constexpr size_t SC_OFF   = WB_BYTES;                     // 256 floats

// exact sign byte (pack_w path): 0x01 if >0, 0xff if <0, 0x00 at +-0
__device__ __forceinline__ uint32_t sgnw(uint32_t u) {
    return (u & 0x7fffffffu) ? (((uint32_t)(((int)u) >> 31) | 1u) & 0xffu) : 0u;
}
// fast sign byte (conv stage): 0x01 if >=+0, 0xff if <0 (R11: passed, 6x headroom)
__device__ __forceinline__ uint32_t sgnb(uint32_t u) {
    return ((uint32_t)(((int)u) >> 31) | 1u) & 0xffu;
}
__device__ __forceinline__ uint32_t pack4f(float4 v) {
    return sgnb(__float_as_uint(v.x)) | (sgnb(__float_as_uint(v.y)) << 8) |
           (sgnb(__float_as_uint(v.z)) << 16) | (sgnb(__float_as_uint(v.w)) << 24);
}

// ---------------- kernel 1: binarize weights into MFMA B-fragment layout ----
__global__ __launch_bounds__(256) void pack_w(const float* __restrict__ wt,
                                              char* __restrict__ wB,
                                              float* __restrict__ scaleg) {
    __shared__ double red[256];
    int o = blockIdx.x, tid = threadIdx.x;
    const float* wo = wt + (size_t)o * 2304;

    double s = 0;
    for (int j = tid; j < 2304; j += 256) s += (double)wo[j];
    red[tid] = s;
    __syncthreads();
    for (int k = 128; k > 0; k >>= 1) {
        if (tid < k) red[tid] += red[tid + k];
        __syncthreads();
    }
    double mean = red[0] / 2304.0;
    __syncthreads();

    double s2 = 0;
    for (int j = tid; j < 2304; j += 256) s2 += fabs((double)wo[j] - mean);
    red[tid] = s2;
    __syncthreads();
    for (int k = 128; k > 0; k >>= 1) {
        if (tid < k) red[tid] += red[tid + k];
        __syncthreads();
    }
    if (tid == 0) scaleg[o] = (float)(red[0] / 2304.0);

    if (tid < 144) {
        int kiter = tid >> 2, q = tid & 3;     // kiter 0..35, q = k-quad
        int tap = kiter >> 2, cb = kiter & 3;
        int kh = tap / 3, kw = tap - kh * 3;
        int words[4];
        for (int g = 0; g < 4; ++g) {
            int word = 0;
            for (int b = 0; b < 4; ++b) {
                int c = cb * 64 + q * 16 + g * 4 + b;
                double v = (double)wo[c * 9 + kh * 3 + kw];
                int sg = (v > mean) - (v < mean);
                word |= (sg & 0xff) << (8 * b);
            }
            words[g] = word;
        }
        v4i pk = {words[0], words[1], words[2], words[3]};
        *(v4i*)(wB + (((size_t)kiter * 16 + (o >> 4)) * 64 + q * 16 + (o & 15)) * 16) = pk;
    }
}

// ---------------- kernel 2: persistent FUSED pack + i8 MFMA conv ------------
// 448 blocks (= 8 x 56, XCD-swizzled) x 256 threads = 4 waves; each block owns
// 4 output rows as TWO iterations of 2. LDS = mod-4 rolling window of 4 input
// rows (59,392 B -> 2 blocks/CU): input row ir always lives at slot ir & 3.
// iter0 stages 4 rows; iter1 stages only the 2 NEW rows (they land exactly in
// the departing rows' slots). Staged rows: 6 per 4 outputs vs 8 before (-25%
// stage work). Engine = proven 28-MFMA cluster + 3-deep counted B ring +
// per-wave k-rotation + setprio; only the row->slot math changed (mod-4).
__global__ __launch_bounds__(256, 2) void conv_mfma(const float* __restrict__ x,
                                                    const v4i* __restrict__ wB,
                                                    const float* __restrict__ scaleg,
                                                    float* __restrict__ out) {
    __shared__ char xs[4 * 58 * 256];   // 59,392 B
    int tid = threadIdx.x;
    int wave = tid >> 6, lane = tid & 63;

    // bijective XCD swizzle: 448 = 8 * 56
    int lin = blockIdx.x + 14 * blockIdx.y;
    int swz = (lin & 7) * 56 + (lin >> 3);
    int hq = swz % 14, n = swz / 14;
    int h0a = hq * 4;                    // outputs h0a..h0a+3 over 2 iterations

    // stage one interior unit: input row ir = ir0 + u/224 -> slot ir & 3
    auto unit = [&](int ir0, int u) {
        int R   = u / 224;
        int rem = u - R * 224;
        int ch  = rem / 14;
        int wq  = rem - ch * 14;
        int ir  = ir0 + R;
        int slot = ir & 3;               // (-1)&3 == 3: virtual halo rows ok
        if (ir < 0 || ir > 55) {
            v4i z = {0, 0, 0, 0};
#pragma unroll
            for (int h = 0; h < 4; ++h) {
                int wp = 1 + wq * 4 + h;
                int s16 = (ch + wp) & 15;
                *(v4i*)(xs + ((size_t)(slot * 58 + wp) << 8) + (s16 << 4)) = z;
            }
            return;
        }
        const float* xb = x + ((size_t)n * C_ + ch * 16) * 3136 + ir * 56 + wq * 4;
        uint32_t sw[16];
#pragma unroll
        for (int c = 0; c < 16; ++c)
            sw[c] = pack4f(*(const float4*)(xb + (size_t)c * 3136));
        uint32_t t[4][4];
#pragma unroll
        for (int p = 0; p < 4; ++p) {
            uint32_t lo01 = __builtin_amdgcn_perm(sw[4*p+1], sw[4*p+0], 0x05010400u);
            uint32_t hi01 = __builtin_amdgcn_perm(sw[4*p+1], sw[4*p+0], 0x07030602u);
            uint32_t lo23 = __builtin_amdgcn_perm(sw[4*p+3], sw[4*p+2], 0x05010400u);
            uint32_t hi23 = __builtin_amdgcn_perm(sw[4*p+3], sw[4*p+2], 0x07030602u);
            t[p][0] = __builtin_amdgcn_perm(lo23, lo01, 0x05040100u);
            t[p][1] = __builtin_amdgcn_perm(lo23, lo01, 0x07060302u);
            t[p][2] = __builtin_amdgcn_perm(hi23, hi01, 0x05040100u);
            t[p][3] = __builtin_amdgcn_perm(hi23, hi01, 0x07060302u);
        }
#pragma unroll
        for (int h = 0; h < 4; ++h) {
            int wp = 1 + wq * 4 + h;
            int s16 = (ch + wp) & 15;
            v4i c4 = {(int)t[0][h], (int)t[1][h], (int)t[2][h], (int)t[3][h]};
            *(v4i*)(xs + ((size_t)(slot * 58 + wp) << 8) + (s16 << 4)) = c4;
        }
    };
    // halo cols wp = 0,57 for staged rows: u in [0, cnt*32)
    auto halo = [&](int ir0, int u) {
        int r  = u >> 5;
        int c2 = u & 31;
        int slot = (ir0 + r) & 3;
        int wp = (c2 >> 4) * 57;
        int ch = c2 & 15;
        int s16 = (ch + wp) & 15;
        v4i z = {0, 0, 0, 0};
        *(v4i*)(xs + ((size_t)(slot * 58 + wp) << 8) + (s16 << 4)) = z;
    };

    // ---- prologue stage: input rows h0a-1 .. h0a+2 (4 rows, 896 units) ----
    if (tid < 128) halo(h0a - 1, tid);
    unit(h0a - 1, tid);
    unit(h0a - 1, tid + 256);
    unit(h0a - 1, tid + 512);
    if (tid < 128) unit(h0a - 1, tid + 768);

    // ---- engine per-lane constants ----
    int lm = lane & 15, q = lane >> 4;
    int og = wave;
    int kstart = __builtin_amdgcn_readfirstlane(wave * 9);   // 0,9,18,27

    int wof[7], ro[7], slotb[7];
#pragma unroll
    for (int mf = 0; mf < 7; ++mf) {
        int m = mf * 16 + lm;            // m = row*56 + w, 0..111
        int r = m / 56;
        ro[mf]    = r;
        wof[mf]   = m - r * 56;
        slotb[mf] = q + wof[mf];
    }

    const v4i* wBw = wB + (size_t)(og * 4) * 64 + lane;   // + k*1024 + of*64

    auto wrap = [&](int t) {
        int k = kstart + t;
        if (k >= 36) k -= 36;
        if (k >= 36) k -= 36;
        return k;
    };
    auto loadB = [&](int k, v4i (&b)[4]) {
#pragma unroll
        for (int of = 0; of < 4; ++of) b[of] = wBw[(size_t)k * 1024 + of * 64];
    };

    // one 2-row iteration of the conv engine at output rows h0it, h0it+1
    auto run_iter = [&](int h0it) {
        v4i acc[7][4];
#pragma unroll
        for (int mf = 0; mf < 7; ++mf)
#pragma unroll
            for (int of = 0; of < 4; ++of) { v4i z = {0, 0, 0, 0}; acc[mf][of] = z; }

        v4i bR0[4], bR1[4], bR2[4];
        loadB(wrap(0), bR0);
        loadB(wrap(1), bR1);
        loadB(wrap(2), bR2);

        auto step = [&](v4i (&bReg)[4], int t) {
            int k = wrap(t);
            int tap = k >> 2, cb = k & 3;
            int dh = (tap * 11) >> 5;        // tap/3 for tap<=8
            int dw = tap - dh * 3;
            int s0 = (h0it - 1 + dh) & 3;    // slot of input row for ro=0
            int s1 = (s0 + 1) & 3;           // slot for ro=1
            int p0 = s0 * 58 + dw;
            int dpr = (s1 - s0) * 58;
            int sofs = cb * 4 + dw;
            v4i a[7];
#pragma unroll
            for (int mf = 0; mf < 7; ++mf) {
                int pos = p0 + ro[mf] * dpr + wof[mf];
                int s16 = (slotb[mf] + sofs) & 15;
                a[mf] = *(const v4i*)(xs + ((size_t)pos << 8) + (s16 << 4));
            }
            __builtin_amdgcn_s_setprio(1);
#pragma unroll
            for (int mf = 0; mf < 7; ++mf)
#pragma unroll
                for (int of = 0; of < 4; ++of)
                    acc[mf][of] = __builtin_amdgcn_mfma_i32_16x16x64_i8(
                        a[mf], bReg[of], acc[mf][of], 0, 0, 0);
            __builtin_amdgcn_s_setprio(0);
            loadB(wrap(t + 3), bReg);        // refill for step t+3
        };

        for (int t3 = 0; t3 < 12; ++t3) {
            int t = t3 * 3;
            step(bR0, t);
            step(bR1, t + 1);
            step(bR2, t + 2);
        }

        // epilogue (global stores; overlaps sibling block's LDS work)
#pragma unroll
        for (int of = 0; of < 4; ++of) {
            int o = (og * 4 + of) * 16 + lm;
            float s = scaleg[o];
#pragma unroll
            for (int mf = 0; mf < 7; ++mf) {
                int m  = mf * 16 + q * 4;
                int r  = m / 56;
                int wb = m - r * 56;
                float* ob = out + ((size_t)(n * C_ + o) * H_ + h0it + r) * W_ + wb;
                float4 v = {s * (float)acc[mf][of].x, s * (float)acc[mf][of].y,
                            s * (float)acc[mf][of].z, s * (float)acc[mf][of].w};
                *(float4*)ob = v;
            }
        }
    };

    __syncthreads();                     // window rows h0a-1..h0a+2 ready
    run_iter(h0a);                       // outputs h0a, h0a+1

    __syncthreads();                     // all waves done reading iter0 rows
    // ---- mid stage: 2 new rows h0a+3, h0a+4 into departing slots ----
    if (tid < 64) halo(h0a + 3, tid);
    unit(h0a + 3, tid);
    if (tid < 192) unit(h0a + 3, tid + 256);
    __syncthreads();                     // window rows h0a+1..h0a+4 ready

    run_iter(h0a + 2);                   // outputs h0a+2, h0a+3
}

extern "C" void kernel_launch(void* const* d_in, const int* in_sizes, int n_in,
                              void* d_out, int out_size, void* d_ws, size_t ws_size,
                              hipStream_t stream) {
    const float* x   = (const float*)d_in[0];
    const float* wgt = (const float*)d_in[1];
    float* out = (float*)d_out;
    char* ws = (char*)d_ws;

    char*  wb = ws;
    float* sg = (float*)(ws + SC_OFF);

    pack_w<<<dim3(256), dim3(256), 0, stream>>>(wgt, wb, sg);
    conv_mfma<<<dim3(14, N_), dim3(256), 0, stream>>>(x, (const v4i*)wb, sg, out);
}